// Round 1
// baseline (455.826 us; speedup 1.0000x reference)
//
#include <hip/hip_runtime.h>

// Problem constants (complete bipartite proxy<->sample + self-loops)
#define PP 100    // proxies
#define NS 1024   // samples
#define NN 1124   // total nodes
#define DD 512    // feature dim
#define CC 100    // fc out dim

// ---------------- fp32 tiled GEMM: C[M,Ncols] = A[M,K] @ B[K,Ncols] (+bias) ---
// A is virtually concat(A0[0:split], A1[split:M]) row-major, K contiguous.
#define BM 64
#define BN 64
#define BK 16

__global__ __launch_bounds__(256) void gemm_kernel(
    const float* __restrict__ A0, const float* __restrict__ A1, int split,
    int M, int Ncols, int K,
    const float* __restrict__ B, const float* __restrict__ bias,
    float* __restrict__ C)
{
  __shared__ float As[BK][BM + 1];  // +1 pad: avoid 16-way bank conflict on store
  __shared__ float Bs[BK][BN];
  const int row0 = blockIdx.y * BM;
  const int col0 = blockIdx.x * BN;
  const int t  = threadIdx.x;
  const int tm = t >> 4;   // 0..15 -> 4 rows each
  const int tn = t & 15;   // 0..15 -> 4 cols each
  const int ka = t & 15;   // A-load: k index
  const int ma = t >> 4;   // A-load: m base
  const int nb = t & 63;   // B-load: n index
  const int kb = t >> 6;   // B-load: k base
  float acc[4][4] = {};

  for (int kt = 0; kt < K; kt += BK) {
    #pragma unroll
    for (int i = 0; i < 4; ++i) {       // A tile: 64(m) x 16(k)
      int m = ma + 16 * i;
      int r = row0 + m;
      float v = 0.f;
      if (r < M) {
        const float* Arow = (r < split) ? (A0 + (size_t)r * K)
                                        : (A1 + (size_t)(r - split) * K);
        v = Arow[kt + ka];
      }
      As[ka][m] = v;
    }
    #pragma unroll
    for (int i = 0; i < 4; ++i) {       // B tile: 16(k) x 64(n)
      int k = kb + 4 * i;
      int cn = col0 + nb;
      float v = 0.f;
      if (cn < Ncols) v = B[(size_t)(kt + k) * Ncols + cn];
      Bs[k][nb] = v;
    }
    __syncthreads();
    #pragma unroll
    for (int k = 0; k < BK; ++k) {
      float a[4], b[4];
      #pragma unroll
      for (int j = 0; j < 4; ++j) a[j] = As[k][tm * 4 + j];
      #pragma unroll
      for (int j = 0; j < 4; ++j) b[j] = Bs[k][tn * 4 + j];
      #pragma unroll
      for (int i2 = 0; i2 < 4; ++i2)
        #pragma unroll
        for (int j2 = 0; j2 < 4; ++j2)
          acc[i2][j2] += a[i2] * b[j2];
    }
    __syncthreads();
  }
  #pragma unroll
  for (int i = 0; i < 4; ++i) {
    int r = row0 + tm * 4 + i;
    if (r >= M) continue;
    #pragma unroll
    for (int j = 0; j < 4; ++j) {
      int cn = col0 + tn * 4 + j;
      if (cn >= Ncols) continue;
      float v = acc[i][j];
      if (bias) v += bias[cn];
      C[(size_t)r * Ncols + cn] = v;
    }
  }
}

// ---------------- per-row attention logits: ls[i]=g[i]·a_src, ld[i]=g[i]·a_dst
__global__ __launch_bounds__(256) void lvec_kernel(
    const float* __restrict__ g, const float* __restrict__ a_src,
    const float* __restrict__ a_dst, float* __restrict__ ls, float* __restrict__ ld)
{
  int row  = blockIdx.x * 4 + (threadIdx.x >> 6);
  int lane = threadIdx.x & 63;
  if (row >= NN) return;
  const float* gr = g + (size_t)row * DD;
  float s1 = 0.f, s2 = 0.f;
  #pragma unroll
  for (int k = lane; k < DD; k += 64) {
    float v = gr[k];
    s1 += v * a_src[k];
    s2 += v * a_dst[k];
  }
  #pragma unroll
  for (int off = 32; off > 0; off >>= 1) {
    s1 += __shfl_down(s1, off);
    s2 += __shfl_down(s2, off);
  }
  if (lane == 0) { ls[row] = s1; ld[row] = s2; }
}

// ---------------- per-dst softmax + weighted aggregation + bias + relu --------
// block = one destination node. i<PP: sources = all samples; else: all proxies.
__global__ __launch_bounds__(256) void agg_kernel(
    const float* __restrict__ g, const float* __restrict__ ls,
    const float* __restrict__ ld, const float* __restrict__ bias,
    float* __restrict__ hout, float* __restrict__ hextra)
{
  const int i = blockIdx.x;
  const bool isProxy = (i < PP);
  const int nsrc = isProxy ? NS : PP;
  const int base = isProxy ? PP : 0;
  __shared__ float sh[NS + 1];   // e / exp(e) per edge; worst case 1025
  __shared__ float red[4];
  const int t = threadIdx.x;
  const float ldi = ld[i];

  // leaky_relu(l_src[src] + l_dst[i], 0.2)
  for (int j = t; j < nsrc; j += 256) {
    float e = ls[base + j] + ldi;
    sh[j] = (e > 0.f) ? e : 0.2f * e;
  }
  if (t == 0) {
    float e = ls[i] + ldi;               // self-loop edge
    sh[nsrc] = (e > 0.f) ? e : 0.2f * e;
  }
  __syncthreads();
  const int ne = nsrc + 1;

  // block max
  float m = -3.4e38f;
  for (int j = t; j < ne; j += 256) m = fmaxf(m, sh[j]);
  #pragma unroll
  for (int off = 32; off > 0; off >>= 1) m = fmaxf(m, __shfl_down(m, off));
  if ((t & 63) == 0) red[t >> 6] = m;
  __syncthreads();
  m = fmaxf(fmaxf(red[0], red[1]), fmaxf(red[2], red[3]));

  // exp and block sum (each thread owns disjoint j's, no race before barrier)
  float psum = 0.f;
  for (int j = t; j < ne; j += 256) {
    float ex = __expf(sh[j] - m);
    sh[j] = ex;
    psum += ex;
  }
  #pragma unroll
  for (int off = 32; off > 0; off >>= 1) psum += __shfl_down(psum, off);
  if ((t & 63) == 0) red[t >> 6] = psum;
  __syncthreads();
  const float inv = 1.f / (red[0] + red[1] + red[2] + red[3]);

  // out[i,d] = (sum_j alpha_j * g[src_j,d]) + b[d], then relu
  const float aself = sh[nsrc];
  for (int d = t; d < DD; d += 256) {
    float acc = aself * g[(size_t)i * DD + d];
    for (int j = 0; j < nsrc; ++j)
      acc += sh[j] * g[(size_t)(base + j) * DD + d];
    acc = acc * inv + bias[d];
    acc = fmaxf(acc, 0.f);
    hout[(size_t)i * DD + d] = acc;
    if (hextra && i >= PP) hextra[(size_t)(i - PP) * DD + d] = acc;
  }
}

extern "C" void kernel_launch(void* const* d_in, const int* in_sizes, int n_in,
                              void* d_out, int out_size, void* d_ws, size_t ws_size,
                              hipStream_t stream)
{
  const float* x    = (const float*)d_in[0];
  const float* prox = (const float*)d_in[1];
  const float* W1   = (const float*)d_in[2];
  const float* as1  = (const float*)d_in[3];
  const float* ad1  = (const float*)d_in[4];
  const float* b1   = (const float*)d_in[5];
  const float* W2   = (const float*)d_in[6];
  const float* as2  = (const float*)d_in[7];
  const float* ad2  = (const float*)d_in[8];
  const float* b2   = (const float*)d_in[9];
  const float* fcw  = (const float*)d_in[10];
  const float* fcb  = (const float*)d_in[11];
  // d_in[12]/d_in[13] (src,dst) unused: graph structure is dense and known.
  float* out = (float*)d_out;

  float* g  = (float*)d_ws;            // [NN,DD] pre-attention features
  float* h1 = g  + (size_t)NN * DD;    // [NN,DD] layer-1 output
  float* h2 = h1 + (size_t)NN * DD;    // [NN,DD] layer-2 output
  float* ls = h2 + (size_t)NN * DD;    // [NN]
  float* ld = ls + NN;                 // [NN]

  dim3 blk(256);
  dim3 gg(DD / BN, (NN + BM - 1) / BM);   // (8,18)

  // layer 1
  gemm_kernel<<<gg, blk, 0, stream>>>(prox, x, PP, NN, DD, DD, W1, nullptr, g);
  lvec_kernel<<<dim3(NN / 4), blk, 0, stream>>>(g, as1, ad1, ls, ld);
  agg_kernel<<<dim3(NN), blk, 0, stream>>>(g, ls, ld, b1, h1, nullptr);
  // layer 2 (rows >= PP of h2 also written straight into d_out's h region)
  gemm_kernel<<<gg, blk, 0, stream>>>(nullptr, h1, 0, NN, DD, DD, W2, nullptr, g);
  lvec_kernel<<<dim3(NN / 4), blk, 0, stream>>>(g, as2, ad2, ls, ld);
  agg_kernel<<<dim3(NN), blk, 0, stream>>>(g, ls, ld, b2, h2,
                                           out + (size_t)NS * CC);
  // fc head: preds[1024,100] = h2[PP:] @ fc_w + fc_b
  dim3 gf((CC + BN - 1) / BN, (NS + BM - 1) / BM);  // (2,16)
  gemm_kernel<<<gf, blk, 0, stream>>>(nullptr, h2 + (size_t)PP * DD, 0,
                                      NS, CC, DD, fcw, fcb, out);
}

// Round 2
// 221.572 us; speedup vs baseline: 2.0572x; 2.0572x over previous
//
#include <hip/hip_runtime.h>

// Problem constants (complete bipartite proxy<->sample + self-loops)
#define PP 100    // proxies
#define NS 1024   // samples
#define NN 1124   // total nodes
#define DD 512    // feature dim
#define CC 100    // fc out dim

// =====================================================================
// Templated fp32 tiled GEMM.
//   C[M,Ncols] = A[M,K] @ B[K,Ncols]   (A = virtual concat(A0[0:split],A1))
// EPI=true adds GAT epilogue: C = relu((acc + esf[r]*S[r*DD+c]) * invZ[r] + bias[c])
// EPI=false: C = acc (+ bias[c] if bias).
// 256 threads; thread computes TM x 4 micro-tile. K must be a multiple of BK.
// =====================================================================
template<int BM, int BN, int BK, int TM, bool EPI>
__global__ __launch_bounds__(256) void gemm_t(
    const float* __restrict__ A0, const float* __restrict__ A1, int split,
    int M, int Ncols, int K,
    const float* __restrict__ B, const float* __restrict__ bias,
    float* __restrict__ C,
    const float* __restrict__ S,
    const float* __restrict__ esf, const float* __restrict__ invZ)
{
  constexpr int TN   = 4;
  constexpr int NCT  = BN / TN;                 // col-thread count (16)
  constexpr int AF4T = BM * BK / 4;             // float4s in A tile
  constexpr int BF4T = BK * BN / 4;
  constexpr int AFP  = (AF4T + 255) / 256;      // per-thread A float4s
  constexpr int BFP  = (BF4T + 255) / 256;
  static_assert(NCT * (BM / TM) == 256, "bad shape");

  __shared__ float As[BK][BM];   // transposed: As[k][m] (k-major for m-contig reads)
  __shared__ float Bs[BK][BN];

  const int t    = threadIdx.x;
  const int row0 = blockIdx.y * BM;
  const int col0 = blockIdx.x * BN;
  const int tn   = t % NCT;
  const int tm   = t / NCT;

  float4 aR[AFP], bR[BFP];

  auto loadA = [&](int kt) {
    #pragma unroll
    for (int p = 0; p < AFP; ++p) {
      int f = t + p * 256;
      float4 v = {0.f, 0.f, 0.f, 0.f};
      if (f < AF4T) {
        int m  = f / (BK / 4);
        int k4 = (f % (BK / 4)) * 4;
        int r  = row0 + m;
        if (r < M) {
          const float* Ar = (r < split) ? (A0 + (size_t)r * K)
                                        : (A1 + (size_t)(r - split) * K);
          v = *(const float4*)(Ar + kt + k4);
        }
      }
      aR[p] = v;
    }
  };
  auto loadB = [&](int kt) {
    #pragma unroll
    for (int p = 0; p < BFP; ++p) {
      int f = t + p * 256;
      float4 v = {0.f, 0.f, 0.f, 0.f};
      if (f < BF4T) {
        int k = f / (BN / 4);
        int c = col0 + (f % (BN / 4)) * 4;
        if (c + 3 < Ncols) v = *(const float4*)(B + (size_t)(kt + k) * Ncols + c);
      }
      bR[p] = v;
    }
  };
  auto storeT = [&]() {
    #pragma unroll
    for (int p = 0; p < AFP; ++p) {
      int f = t + p * 256;
      if (f < AF4T) {
        int m  = f / (BK / 4);
        int k4 = (f % (BK / 4)) * 4;
        As[k4 + 0][m] = aR[p].x;
        As[k4 + 1][m] = aR[p].y;
        As[k4 + 2][m] = aR[p].z;
        As[k4 + 3][m] = aR[p].w;
      }
    }
    #pragma unroll
    for (int p = 0; p < BFP; ++p) {
      int f = t + p * 256;
      if (f < BF4T) {
        int k  = f / (BN / 4);
        int c4 = (f % (BN / 4)) * 4;
        *(float4*)&Bs[k][c4] = bR[p];
      }
    }
  };

  float acc[TM][TN] = {};
  loadA(0); loadB(0);
  storeT();
  __syncthreads();

  for (int kt = BK; kt < K + BK; kt += BK) {
    const bool more = (kt < K);
    if (more) { loadA(kt); loadB(kt); }   // in-flight during compute
    #pragma unroll
    for (int k = 0; k < BK; ++k) {
      float a[TM];
      if constexpr (TM == 4) {
        float4 av = *(const float4*)&As[k][tm * 4];
        a[0] = av.x; a[1] = av.y; a[2] = av.z; a[3] = av.w;
      } else {
        a[0] = As[k][tm];
      }
      float4 bv = *(const float4*)&Bs[k][tn * 4];
      float b[4] = {bv.x, bv.y, bv.z, bv.w};
      #pragma unroll
      for (int i = 0; i < TM; ++i)
        #pragma unroll
        for (int j = 0; j < 4; ++j)
          acc[i][j] = fmaf(a[i], b[j], acc[i][j]);
    }
    __syncthreads();
    if (more) { storeT(); __syncthreads(); }
  }

  #pragma unroll
  for (int i = 0; i < TM; ++i) {
    int r = row0 + tm * TM + i;
    if (r >= M) continue;
    float sv = 0.f, iz = 0.f;
    if constexpr (EPI) { sv = esf[r]; iz = invZ[r]; }
    #pragma unroll
    for (int j = 0; j < 4; ++j) {
      int c = col0 + tn * 4 + j;
      if (c >= Ncols) continue;
      float v = acc[i][j];
      if constexpr (EPI) {
        v = (v + sv * S[(size_t)r * DD + c]) * iz + bias[c];
        v = fmaxf(v, 0.f);
      } else {
        if (bias) v += bias[c];
      }
      C[(size_t)r * Ncols + c] = v;
    }
  }
}

// ---------------- per-row attention logits: ls[i]=g[i]·a_src, ld[i]=g[i]·a_dst
__global__ __launch_bounds__(256) void lvec_kernel(
    const float* __restrict__ g, const float* __restrict__ a_src,
    const float* __restrict__ a_dst, float* __restrict__ ls, float* __restrict__ ld)
{
  int row  = blockIdx.x * 4 + (threadIdx.x >> 6);
  int lane = threadIdx.x & 63;
  if (row >= NN) return;
  const float4* gr = (const float4*)(g + (size_t)row * DD);
  const float4* s4 = (const float4*)a_src;
  const float4* d4 = (const float4*)a_dst;
  float s1 = 0.f, s2 = 0.f;
  #pragma unroll
  for (int f = lane; f < DD / 4; f += 64) {
    float4 v = gr[f], a = s4[f], b = d4[f];
    s1 += v.x * a.x + v.y * a.y + v.z * a.z + v.w * a.w;
    s2 += v.x * b.x + v.y * b.y + v.z * b.z + v.w * b.w;
  }
  #pragma unroll
  for (int off = 32; off > 0; off >>= 1) {
    s1 += __shfl_down(s1, off);
    s2 += __shfl_down(s2, off);
  }
  if (lane == 0) { ls[row] = s1; ld[row] = s2; }
}

// ---------------- softmax weights (unnormalized exp) ------------------------
// blocks [0,256): wave-per-sample-dst -> Es[1024,128] (cols 100..127 zero-pad),
//                 esS (self exp), invZS.
// blocks [256,256+PP): block-per-proxy-dst -> Ep[100,1024], esP, invZP.
__global__ __launch_bounds__(256) void alpha_kernel(
    const float* __restrict__ ls, const float* __restrict__ ld,
    float* __restrict__ Es, float* __restrict__ esS, float* __restrict__ invZS,
    float* __restrict__ Ep, float* __restrict__ esP, float* __restrict__ invZP)
{
  const int t = threadIdx.x;
  auto lk = [](float v) { return v > 0.f ? v : 0.2f * v; };
  if (blockIdx.x < 256) {
    const int lane = t & 63;
    const int i = blockIdx.x * 4 + (t >> 6);     // sample dst index
    const float ldi = ld[PP + i];
    float e0 = (lane      < PP) ? lk(ls[lane]      + ldi) : -1e30f;
    float e1 = (lane + 64 < PP) ? lk(ls[lane + 64] + ldi) : -1e30f;
    const float eself = lk(ls[PP + i] + ldi);
    float m = fmaxf(fmaxf(e0, e1), eself);
    #pragma unroll
    for (int off = 32; off > 0; off >>= 1) m = fmaxf(m, __shfl_down(m, off));
    m = __shfl(m, 0);
    float x0 = (lane      < PP) ? __expf(e0 - m) : 0.f;
    float x1 = (lane + 64 < PP) ? __expf(e1 - m) : 0.f;
    float z = x0 + x1;
    #pragma unroll
    for (int off = 32; off > 0; off >>= 1) z += __shfl_down(z, off);
    Es[(size_t)i * 128 + lane]      = x0;
    Es[(size_t)i * 128 + 64 + lane] = x1;
    if (lane == 0) {
      float xs = __expf(eself - m);
      esS[i]   = xs;
      invZS[i] = 1.f / (z + xs);
    }
  } else {
    const int i = blockIdx.x - 256;              // proxy dst index
    const float ldi = ld[i];
    float e[4];
    #pragma unroll
    for (int q = 0; q < 4; ++q) e[q] = lk(ls[PP + t + q * 256] + ldi);
    const float eself = lk(ls[i] + ldi);
    __shared__ float red[4];
    float m = fmaxf(fmaxf(fmaxf(e[0], e[1]), fmaxf(e[2], e[3])), eself);
    #pragma unroll
    for (int off = 32; off > 0; off >>= 1) m = fmaxf(m, __shfl_down(m, off));
    if ((t & 63) == 0) red[t >> 6] = m;
    __syncthreads();
    m = fmaxf(fmaxf(red[0], red[1]), fmaxf(red[2], red[3]));
    __syncthreads();
    float x[4], z = 0.f;
    #pragma unroll
    for (int q = 0; q < 4; ++q) { x[q] = __expf(e[q] - m); z += x[q]; }
    #pragma unroll
    for (int off = 32; off > 0; off >>= 1) z += __shfl_down(z, off);
    if ((t & 63) == 0) red[t >> 6] = z;
    __syncthreads();
    #pragma unroll
    for (int q = 0; q < 4; ++q) Ep[(size_t)i * NS + t + q * 256] = x[q];
    if (t == 0) {
      float xs = __expf(eself - m);
      esP[i]   = xs;
      invZP[i] = 1.f / (red[0] + red[1] + red[2] + red[3] + xs);
    }
  }
}

extern "C" void kernel_launch(void* const* d_in, const int* in_sizes, int n_in,
                              void* d_out, int out_size, void* d_ws, size_t ws_size,
                              hipStream_t stream)
{
  const float* x    = (const float*)d_in[0];
  const float* prox = (const float*)d_in[1];
  const float* W1   = (const float*)d_in[2];
  const float* as1  = (const float*)d_in[3];
  const float* ad1  = (const float*)d_in[4];
  const float* b1   = (const float*)d_in[5];
  const float* W2   = (const float*)d_in[6];
  const float* as2  = (const float*)d_in[7];
  const float* ad2  = (const float*)d_in[8];
  const float* b2   = (const float*)d_in[9];
  const float* fcw  = (const float*)d_in[10];
  const float* fcb  = (const float*)d_in[11];
  float* out = (float*)d_out;

  float* g   = (float*)d_ws;                 // [NN,DD] pre-attention features
  float* h1  = g   + (size_t)NN * DD;        // [NN,DD] layer-1 output
  float* Es  = h1  + (size_t)NN * DD;        // [NS,128] sample-dst exp weights (padded)
  float* Ep  = Es  + (size_t)NS * 128;       // [PP,NS] proxy-dst exp weights
  float* esS = Ep  + (size_t)PP * NS;        // [NS] self exp (sample)
  float* izS = esS + NS;                     // [NS] 1/Z (sample)
  float* esP = izS + NS;                     // [128]
  float* izP = esP + 128;                    // [128]
  float* ls  = izP + 128;                    // [NN]
  float* ld  = ls  + NN;                     // [NN]

  dim3 blk(256);
  float* gs  = g + (size_t)PP * DD;          // sample rows of g
  float* h2s = out + (size_t)NS * CC;        // layer-2 sample output lives in d_out

  // ---- layer 1
  gemm_t<64,64,32,4,false><<<dim3(8,18), blk, 0, stream>>>(
      prox, x, PP, NN, DD, DD, W1, nullptr, g, nullptr, nullptr, nullptr);
  lvec_kernel<<<281, blk, 0, stream>>>(g, as1, ad1, ls, ld);
  alpha_kernel<<<256 + PP, blk, 0, stream>>>(ls, ld, Es, esS, izS, Ep, esP, izP);
  // sample-dst aggregation: Es[1024,128] @ g_prox[<=128,512]  (pad rows hit zeros in Es)
  gemm_t<64,64,32,4,true><<<dim3(8,16), blk, 0, stream>>>(
      Es, Es, NS, NS, DD, 128, g, b1, h1 + (size_t)PP * DD, gs, esS, izS);
  // proxy-dst aggregation: Ep[100,1024] @ g_samp[1024,512]
  gemm_t<16,64,32,1,true><<<dim3(8,7), blk, 0, stream>>>(
      Ep, Ep, PP, PP, DD, NS, gs, b1, h1, g, esP, izP);

  // ---- layer 2 (proxy-dst aggregation is dead code: outputs only need rows P:)
  gemm_t<64,64,32,4,false><<<dim3(8,18), blk, 0, stream>>>(
      h1, h1, NN, NN, DD, DD, W2, nullptr, g, nullptr, nullptr, nullptr);
  lvec_kernel<<<281, blk, 0, stream>>>(g, as2, ad2, ls, ld);
  alpha_kernel<<<256, blk, 0, stream>>>(ls, ld, Es, esS, izS, Ep, esP, izP);
  gemm_t<64,64,32,4,true><<<dim3(8,16), blk, 0, stream>>>(
      Es, Es, NS, NS, DD, 128, g, b2, h2s, gs, esS, izS);

  // ---- fc head: preds[1024,100] = h2_samp @ fc_w + fc_b
  gemm_t<64,64,32,4,false><<<dim3(2,16), blk, 0, stream>>>(
      h2s, h2s, NS, NS, CC, DD, fcw, fcb, out, nullptr, nullptr, nullptr);
}